// Round 1
// baseline (1193.753 us; speedup 1.0000x reference)
//
#include <hip/hip_runtime.h>
#include <hip/hip_bf16.h>

#define Nn 20000
#define Dd 256
#define Ff 256
#define Kc 32

typedef __attribute__((ext_vector_type(8))) short short8;
typedef __attribute__((ext_vector_type(4))) short short4_t;
typedef __attribute__((ext_vector_type(4))) float float4_t;

static __device__ __forceinline__ short f2bf(float x) {
    union { float f; unsigned u; } v; v.f = x;
    unsigned r = v.u + 0x7FFFu + ((v.u >> 16) & 1u);   // round-to-nearest-even
    return (short)(r >> 16);
}

// ---------------- K1: node = h @ W1  [N,32] fp32 ----------------
__global__ __launch_bounds__(256) void k_node(const float* __restrict__ h,
                                              const float* __restrict__ W1,
                                              float* __restrict__ node) {
    int t = blockIdx.x * 256 + threadIdx.x;     // N*32 threads
    int n = t >> 5, k = t & 31;
    if (n >= Nn) return;
    const float4_t* hr = (const float4_t*)(h + (size_t)n * Dd);
    float s = 0.f;
    #pragma unroll 8
    for (int d4 = 0; d4 < 64; ++d4) {
        float4_t hv = hr[d4];
        #pragma unroll
        for (int j = 0; j < 4; ++j) s += hv[j] * W1[(d4 * 4 + j) * Kc + k];
    }
    node[n * Kc + k] = s;
}

// ------- K2: pack W2 (fp32 [32][256][256]) -> bf16 B-fragment order -------
// P[(((kk*8+dc)*16+cf)*64+lane)*8 + j] = bf16(W2[kk][dc*32+(lane>>4)*8+j][cf*16+(lane&15)])
__global__ __launch_bounds__(256) void k_packW2(const float* __restrict__ W2,
                                                short* __restrict__ P) {
    int t = blockIdx.x * 256 + threadIdx.x;     // 262144 threads
    int lane = t & 63;
    int cf = (t >> 6) & 15;
    int dc = (t >> 10) & 7;
    int kk = t >> 13;
    int col = cf * 16 + (lane & 15);
    int d0  = dc * 32 + (lane >> 4) * 8;
    const float* src = W2 + ((size_t)(kk * Dd + d0)) * Ff + col;
    short8 v;
    #pragma unroll
    for (int j = 0; j < 8; ++j) v[j] = f2bf(src[(size_t)j * Ff]);
    *(short8*)(P + (size_t)t * 8) = v;
}

// ---------------- K3: x_pre, stored transposed bf16 [256][20000] ----------------
// x_pre[n,f] = sum_kk node[n,kk] * (h[n,:] @ W2[kk,:,:])[f]
__global__ __launch_bounds__(256, 2) void k_xpre(const float* __restrict__ h,
                                                 const float* __restrict__ node,
                                                 const short* __restrict__ P,
                                                 short* __restrict__ xpre_t) {
    __shared__ short hlds[64 * 264];        // bf16 h tile, padded stride 264
    __shared__ float ntl[32 * 64];          // node transposed [kk][n_local]
    int t = threadIdx.x;
    int n0 = blockIdx.x * 64;

    // stage h tile (fp32 -> bf16)
    #pragma unroll
    for (int i = 0; i < 16; ++i) {
        int c = t + i * 256;                // 4096 float4 chunks
        int row = c >> 6, cc = c & 63;
        int n = n0 + row; if (n > Nn - 1) n = Nn - 1;
        float4_t v = *(const float4_t*)(h + (size_t)n * Dd + cc * 4);
        short4_t bv;
        #pragma unroll
        for (int j = 0; j < 4; ++j) bv[j] = f2bf(v[j]);
        *(short4_t*)&hlds[row * 264 + cc * 4] = bv;
    }
    // stage node transposed
    #pragma unroll
    for (int i = 0; i < 8; ++i) {
        int idx = t + i * 256;              // 2048
        int nl = idx >> 5, k = idx & 31;
        int n = n0 + nl; if (n > Nn - 1) n = Nn - 1;
        ntl[k * 64 + nl] = node[(size_t)n * Kc + k];
    }
    __syncthreads();

    int lane = t & 63, w = t >> 6;
    int arow = lane & 15;
    int asel = (lane >> 4) * 8;
    float4_t acc[4][4];
    #pragma unroll
    for (int a = 0; a < 4; ++a)
        #pragma unroll
        for (int b2 = 0; b2 < 4; ++b2) acc[a][b2] = (float4_t){0.f, 0.f, 0.f, 0.f};

    for (int kk = 0; kk < 32; ++kk) {
        float4_t T[4][4];
        #pragma unroll
        for (int a = 0; a < 4; ++a)
            #pragma unroll
            for (int b2 = 0; b2 < 4; ++b2) T[a][b2] = (float4_t){0.f, 0.f, 0.f, 0.f};
        #pragma unroll
        for (int dc = 0; dc < 8; ++dc) {
            short8 af[4], bfr[4];
            #pragma unroll
            for (int rf = 0; rf < 4; ++rf)
                af[rf] = *(const short8*)&hlds[(rf * 16 + arow) * 264 + dc * 32 + asel];
            #pragma unroll
            for (int cf = 0; cf < 4; ++cf)
                bfr[cf] = *(const short8*)(P + ((size_t)(((kk * 8 + dc) * 16 + w * 4 + cf) * 64 + lane)) * 8);
            #pragma unroll
            for (int rf = 0; rf < 4; ++rf)
                #pragma unroll
                for (int cf = 0; cf < 4; ++cf)
                    T[rf][cf] = __builtin_amdgcn_mfma_f32_16x16x32_bf16(af[rf], bfr[cf], T[rf][cf], 0, 0, 0);
        }
        // scale-accumulate by node[:,kk]
        #pragma unroll
        for (int rf = 0; rf < 4; ++rf) {
            float4_t sc = *(const float4_t*)&ntl[kk * 64 + rf * 16 + (lane >> 4) * 4];
            #pragma unroll
            for (int cf = 0; cf < 4; ++cf)
                #pragma unroll
                for (int r = 0; r < 4; ++r)
                    acc[rf][cf][r] += sc[r] * T[rf][cf][r];
        }
    }

    // store transposed: xpre_t[f][n]
    #pragma unroll
    for (int rf = 0; rf < 4; ++rf) {
        int nl = rf * 16 + (lane >> 4) * 4;
        #pragma unroll
        for (int cf = 0; cf < 4; ++cf) {
            int f = w * 64 + cf * 16 + (lane & 15);
            #pragma unroll
            for (int r = 0; r < 4; ++r) {
                int n = n0 + nl + r;
                if (n < Nn) xpre_t[(size_t)f * Nn + n] = f2bf(acc[rf][cf][r]);
            }
        }
    }
}

// ---------------- K4: out = relu(adj @ x_pre + node @ b) ----------------
// BM=80 (250 blocks), BN=256, BK=32, 512 threads (8 waves x 32 cols)
__global__ __launch_bounds__(512, 2) void k_aggr(const float* __restrict__ adj,
                                                 const short* __restrict__ xpre_t,
                                                 const float* __restrict__ node,
                                                 const float* __restrict__ b,
                                                 float* __restrict__ out) {
    __shared__ short alds[2][80 * 40];      // adj tile bf16, stride 40
    __shared__ short xlds[2][256 * 40];     // xpre tile [f][k] bf16, stride 40
    __shared__ float nlds[80 * 32];         // node tile fp32
    __shared__ float blds[32 * 256];        // b fp32

    int t = threadIdx.x;
    int m0 = blockIdx.x * 80;
    int ra = t >> 5, ca = t & 31;           // adj staging coords
    int fa = t >> 2, c8 = t & 3;            // xpre staging coords

    // stage node tile and b (read in epilogue; ordered by loop barriers)
    #pragma unroll
    for (int i = 0; i < 5; ++i) { int idx = t + i * 512; nlds[idx] = node[(size_t)m0 * 32 + idx]; }
    #pragma unroll
    for (int i = 0; i < 4; ++i) { int idx = t + i * 512; *(float4_t*)&blds[idx * 4] = *(const float4_t*)(b + (size_t)idx * 4); }

    float av0, av1, av2, av3, av4;
    short8 xv0, xv1;

#define K4_LOAD(step_) do { \
        long base_ = (long)m0 * 20000 + (long)(step_) * 32 + ca; \
        av0 = adj[base_ + (long)(ra +  0) * 20000]; \
        av1 = adj[base_ + (long)(ra + 16) * 20000]; \
        av2 = adj[base_ + (long)(ra + 32) * 20000]; \
        av3 = adj[base_ + (long)(ra + 48) * 20000]; \
        av4 = adj[base_ + (long)(ra + 64) * 20000]; \
        const short* xb_ = xpre_t + (long)(step_) * 32 + c8 * 8; \
        xv0 = *(const short8*)(xb_ + (long)(fa +   0) * 20000); \
        xv1 = *(const short8*)(xb_ + (long)(fa + 128) * 20000); \
    } while (0)

#define K4_WRITE(buf_) do { \
        alds[buf_][(ra +  0) * 40 + ca] = f2bf(av0); \
        alds[buf_][(ra + 16) * 40 + ca] = f2bf(av1); \
        alds[buf_][(ra + 32) * 40 + ca] = f2bf(av2); \
        alds[buf_][(ra + 48) * 40 + ca] = f2bf(av3); \
        alds[buf_][(ra + 64) * 40 + ca] = f2bf(av4); \
        *(short8*)&xlds[buf_][(fa +   0) * 40 + c8 * 8] = xv0; \
        *(short8*)&xlds[buf_][(fa + 128) * 40 + c8 * 8] = xv1; \
    } while (0)

    int lane = t & 63, w = t >> 6;
    float4_t acc[5][2];
    #pragma unroll
    for (int rf = 0; rf < 5; ++rf)
        #pragma unroll
        for (int cf = 0; cf < 2; ++cf) acc[rf][cf] = (float4_t){0.f, 0.f, 0.f, 0.f};

    K4_LOAD(0);
    int cur = 0;
    for (int step = 0; step < 625; ++step) {
        K4_WRITE(cur);
        __syncthreads();
        if (step != 624) K4_LOAD(step + 1);   // issue-early: fly under MFMA

        short8 bfr0 = *(const short8*)&xlds[cur][(w * 32 +  0 + (lane & 15)) * 40 + (lane >> 4) * 8];
        short8 bfr1 = *(const short8*)&xlds[cur][(w * 32 + 16 + (lane & 15)) * 40 + (lane >> 4) * 8];
        #pragma unroll
        for (int rf = 0; rf < 5; ++rf) {
            short8 afr = *(const short8*)&alds[cur][(rf * 16 + (lane & 15)) * 40 + (lane >> 4) * 8];
            acc[rf][0] = __builtin_amdgcn_mfma_f32_16x16x32_bf16(afr, bfr0, acc[rf][0], 0, 0, 0);
            acc[rf][1] = __builtin_amdgcn_mfma_f32_16x16x32_bf16(afr, bfr1, acc[rf][1], 0, 0, 0);
        }
        __syncthreads();
        cur ^= 1;
    }

    // epilogue: + node@b, relu, store fp32
    #pragma unroll
    for (int rf = 0; rf < 5; ++rf) {
        #pragma unroll
        for (int cf = 0; cf < 2; ++cf) {
            int fl = w * 32 + cf * 16 + (lane & 15);
            #pragma unroll
            for (int r = 0; r < 4; ++r) {
                int nl = rf * 16 + (lane >> 4) * 4 + r;
                float bias = 0.f;
                #pragma unroll 8
                for (int k = 0; k < 32; ++k) bias += nlds[nl * 32 + k] * blds[k * 256 + fl];
                float v = acc[rf][cf][r] + bias;
                out[(size_t)(m0 + nl) * 256 + fl] = v > 0.f ? v : 0.f;
            }
        }
    }
#undef K4_LOAD
#undef K4_WRITE
}

extern "C" void kernel_launch(void* const* d_in, const int* in_sizes, int n_in,
                              void* d_out, int out_size, void* d_ws, size_t ws_size,
                              hipStream_t stream) {
    const float* h   = (const float*)d_in[0];
    const float* adj = (const float*)d_in[1];
    const float* W1  = (const float*)d_in[2];
    const float* W2  = (const float*)d_in[3];
    const float* b   = (const float*)d_in[4];
    float* out = (float*)d_out;

    char* ws = (char*)d_ws;
    float* node   = (float*)ws;                               // 2,560,000 B
    short* P      = (short*)(ws + 2560000);                   // 4,194,304 B
    short* xpre_t = (short*)(ws + 2560000 + 4194304);         // 10,240,000 B

    k_node  <<<2500, 256, 0, stream>>>(h, W1, node);
    k_packW2<<<1024, 256, 0, stream>>>(W2, P);
    k_xpre  <<<313,  256, 0, stream>>>(h, node, P, xpre_t);
    k_aggr  <<<250,  512, 0, stream>>>(adj, xpre_t, node, b, out);
}

// Round 2
// 876.645 us; speedup vs baseline: 1.3617x; 1.3617x over previous
//
#include <hip/hip_runtime.h>
#include <hip/hip_bf16.h>

#define Nn 20000
#define Dd 256
#define Ff 256
#define Kc 32

typedef __attribute__((ext_vector_type(8))) short short8;
typedef __attribute__((ext_vector_type(4))) short short4_t;
typedef __attribute__((ext_vector_type(4))) float float4_t;

static __device__ __forceinline__ short f2bf(float x) {
    union { float f; unsigned u; } v; v.f = x;
    unsigned r = v.u + 0x7FFFu + ((v.u >> 16) & 1u);   // round-to-nearest-even
    return (short)(r >> 16);
}
static __device__ __forceinline__ short4_t cvt4(float4_t v) {
    short4_t r; r[0] = f2bf(v[0]); r[1] = f2bf(v[1]); r[2] = f2bf(v[2]); r[3] = f2bf(v[3]);
    return r;
}

// ---------------- K1: node = h @ W1  [N,32] fp32 ----------------
__global__ __launch_bounds__(256) void k_node(const float* __restrict__ h,
                                              const float* __restrict__ W1,
                                              float* __restrict__ node) {
    int t = blockIdx.x * 256 + threadIdx.x;     // N*32 threads
    int n = t >> 5, k = t & 31;
    if (n >= Nn) return;
    const float4_t* hr = (const float4_t*)(h + (size_t)n * Dd);
    float s = 0.f;
    #pragma unroll 8
    for (int d4 = 0; d4 < 64; ++d4) {
        float4_t hv = hr[d4];
        #pragma unroll
        for (int j = 0; j < 4; ++j) s += hv[j] * W1[(d4 * 4 + j) * Kc + k];
    }
    node[n * Kc + k] = s;
}

// ------- K2: pack W2 (fp32 [32][256][256]) -> bf16 B-fragment order -------
__global__ __launch_bounds__(256) void k_packW2(const float* __restrict__ W2,
                                                short* __restrict__ P) {
    int t = blockIdx.x * 256 + threadIdx.x;     // 262144 threads
    int lane = t & 63;
    int cf = (t >> 6) & 15;
    int dc = (t >> 10) & 7;
    int kk = t >> 13;
    int col = cf * 16 + (lane & 15);
    int d0  = dc * 32 + (lane >> 4) * 8;
    const float* src = W2 + ((size_t)(kk * Dd + d0)) * Ff + col;
    short8 v;
    #pragma unroll
    for (int j = 0; j < 8; ++j) v[j] = f2bf(src[(size_t)j * Ff]);
    *(short8*)(P + (size_t)t * 8) = v;
}

// ---------------- K3: x_pre, stored transposed bf16 [256][20000] ----------------
__global__ __launch_bounds__(256, 2) void k_xpre(const float* __restrict__ h,
                                                 const float* __restrict__ node,
                                                 const short* __restrict__ P,
                                                 short* __restrict__ xpre_t) {
    __shared__ short hlds[64 * 264];        // bf16 h tile, padded stride 264
    __shared__ float ntl[32 * 64];          // node transposed [kk][n_local]
    int t = threadIdx.x;
    int n0 = blockIdx.x * 64;

    #pragma unroll
    for (int i = 0; i < 16; ++i) {
        int c = t + i * 256;                // 4096 float4 chunks
        int row = c >> 6, cc = c & 63;
        int n = n0 + row; if (n > Nn - 1) n = Nn - 1;
        float4_t v = *(const float4_t*)(h + (size_t)n * Dd + cc * 4);
        *(short4_t*)&hlds[row * 264 + cc * 4] = cvt4(v);
    }
    #pragma unroll
    for (int i = 0; i < 8; ++i) {
        int idx = t + i * 256;              // 2048
        int nl = idx >> 5, k = idx & 31;
        int n = n0 + nl; if (n > Nn - 1) n = Nn - 1;
        ntl[k * 64 + nl] = node[(size_t)n * Kc + k];
    }
    __syncthreads();

    int lane = t & 63, w = t >> 6;
    int arow = lane & 15;
    int asel = (lane >> 4) * 8;
    float4_t acc[4][4];
    #pragma unroll
    for (int a = 0; a < 4; ++a)
        #pragma unroll
        for (int b2 = 0; b2 < 4; ++b2) acc[a][b2] = (float4_t){0.f, 0.f, 0.f, 0.f};

    for (int kk = 0; kk < 32; ++kk) {
        float4_t T[4][4];
        #pragma unroll
        for (int a = 0; a < 4; ++a)
            #pragma unroll
            for (int b2 = 0; b2 < 4; ++b2) T[a][b2] = (float4_t){0.f, 0.f, 0.f, 0.f};
        #pragma unroll
        for (int dc = 0; dc < 8; ++dc) {
            short8 af[4], bfr[4];
            #pragma unroll
            for (int rf = 0; rf < 4; ++rf)
                af[rf] = *(const short8*)&hlds[(rf * 16 + arow) * 264 + dc * 32 + asel];
            #pragma unroll
            for (int cf = 0; cf < 4; ++cf)
                bfr[cf] = *(const short8*)(P + ((size_t)(((kk * 8 + dc) * 16 + w * 4 + cf) * 64 + lane)) * 8);
            #pragma unroll
            for (int rf = 0; rf < 4; ++rf)
                #pragma unroll
                for (int cf = 0; cf < 4; ++cf)
                    T[rf][cf] = __builtin_amdgcn_mfma_f32_16x16x32_bf16(af[rf], bfr[cf], T[rf][cf], 0, 0, 0);
        }
        #pragma unroll
        for (int rf = 0; rf < 4; ++rf) {
            float4_t sc = *(const float4_t*)&ntl[kk * 64 + rf * 16 + (lane >> 4) * 4];
            #pragma unroll
            for (int cf = 0; cf < 4; ++cf)
                #pragma unroll
                for (int r = 0; r < 4; ++r)
                    acc[rf][cf][r] += sc[r] * T[rf][cf][r];
        }
    }

    #pragma unroll
    for (int rf = 0; rf < 4; ++rf) {
        int nl = rf * 16 + (lane >> 4) * 4;
        #pragma unroll
        for (int cf = 0; cf < 4; ++cf) {
            int f = w * 64 + cf * 16 + (lane & 15);
            #pragma unroll
            for (int r = 0; r < 4; ++r) {
                int n = n0 + nl + r;
                if (n < Nn) xpre_t[(size_t)f * Nn + n] = f2bf(acc[rf][cf][r]);
            }
        }
    }
}

// ---------------- K4: out = relu(adj @ x_pre + node @ b) ----------------
// BM=80 (250 blocks), BN=256, BK=160 (125 steps), 512 threads (8 waves)
// adj: 2-step-ahead register pipeline -> bf16 -> LDS (dbuf, 1 barrier/step)
// xpre B-frags: direct from global (L2/L3-resident), 1-step-ahead reg dbuf
#define BM 80
#define BK 160
#define ASTR 168            // alds row stride in shorts (336B = 21*16, b128-aligned)
#define NSTEP 125

__global__ __launch_bounds__(512, 2) void k_aggr(const float* __restrict__ adj,
                                                 const short* __restrict__ xpre_t,
                                                 const float* __restrict__ node,
                                                 const float* __restrict__ bb,
                                                 float* __restrict__ out) {
    __shared__ short alds[2][BM * ASTR];    // 2 x 26.9 KB
    __shared__ float nlds[BM * 32];         // 10.24 KB
    __shared__ float blds[32 * 256];        // 32.77 KB

    const int t = threadIdx.x;
    const int m0 = blockIdx.x * BM;
    const int lane = t & 63, w = t >> 6;
    const int kb = (lane >> 4) * 8;

    // stage node tile + b for the epilogue
    #pragma unroll
    for (int i = 0; i < 5; ++i) { int idx = t + i * 512; nlds[idx] = node[(size_t)m0 * 32 + idx]; }
    #pragma unroll
    for (int i = 0; i < 4; ++i) { int idx = t + i * 512; *(float4_t*)&blds[idx * 4] = *(const float4_t*)(bb + (size_t)idx * 4); }

    // adj staging geometry: 80*160 floats = 3200 float4 chunks/step; 6-7 per thread
    const bool val7 = (t < 128);
    long gbase[7]; int loff[7];
    #pragma unroll
    for (int i = 0; i < 7; ++i) {
        int c = t + i * 512; if (c >= 3200) c = 0;
        int row = c / 40, col = c % 40;     // 40 float4 per row
        gbase[i] = (long)(m0 + row) * Nn + col * 4;
        loff[i]  = row * ASTR + col * 4;
    }
    // xpre B-frag bases (this wave's two 16-col fragments)
    const long xb0 = (long)(w * 32 + (lane & 15)) * Nn + kb;
    const long xb1 = xb0 + 16L * Nn;

#define LOADA(dst, s_) do { _Pragma("unroll") for (int i = 0; i < 7; ++i) \
        if (i < 6 || val7) dst[i] = *(const float4_t*)(adj + gbase[i] + (long)(s_) * BK); } while (0)

#define WRITEA(src, buf_) do { _Pragma("unroll") for (int i = 0; i < 7; ++i) \
        if (i < 6 || val7) *(short4_t*)&alds[buf_][loff[i]] = cvt4(src[i]); } while (0)

#define LOADB(d0_, d1_, s_) do { _Pragma("unroll") for (int dc = 0; dc < 5; ++dc) { \
        d0_[dc] = *(const short8*)(xpre_t + xb0 + (long)(s_) * BK + dc * 32); \
        d1_[dc] = *(const short8*)(xpre_t + xb1 + (long)(s_) * BK + dc * 32); } } while (0)

#define COMPUTE(buf_, B0_, B1_) do { _Pragma("unroll") for (int dc = 0; dc < 5; ++dc) { \
        _Pragma("unroll") for (int rf = 0; rf < 5; ++rf) { \
            short8 afr = *(const short8*)&alds[buf_][(rf * 16 + (lane & 15)) * ASTR + dc * 32 + kb]; \
            acc[rf][0] = __builtin_amdgcn_mfma_f32_16x16x32_bf16(afr, B0_[dc], acc[rf][0], 0, 0, 0); \
            acc[rf][1] = __builtin_amdgcn_mfma_f32_16x16x32_bf16(afr, B1_[dc], acc[rf][1], 0, 0, 0); } } } while (0)

    float4_t acc[5][2];
    #pragma unroll
    for (int rf = 0; rf < 5; ++rf)
        #pragma unroll
        for (int cf = 0; cf < 2; ++cf) acc[rf][cf] = (float4_t){0.f, 0.f, 0.f, 0.f};

    float4_t A0[7], A1[7];
    short8 BA0[5], BA1[5], BB0[5], BB1[5];

    // prologue: fill both adj reg sets + first B set; commit step 0 to LDS
    LOADA(A0, 0);
    LOADA(A1, 1);
    LOADB(BA0, BA1, 0);
    WRITEA(A0, 0);                       // waits only A0's loads (counted vmcnt)
    __syncthreads();

    #pragma unroll 1
    for (int p = 0; p < 62; ++p) {
        const int s0 = 2 * p;
        // even step s0: compute buf0 with BA; prefetch A(s0+2), B(s0+1)
        LOADA(A0, s0 + 2);
        LOADB(BB0, BB1, s0 + 1);
        COMPUTE(0, BA0, BA1);
        WRITEA(A1, 1);                   // commit step s0+1
        __syncthreads();
        // odd step s0+1: compute buf1 with BB; prefetch A(s0+3), B(s0+2)
        if (s0 + 3 < NSTEP) LOADA(A1, s0 + 3);
        LOADB(BA0, BA1, s0 + 2);
        COMPUTE(1, BB0, BB1);
        WRITEA(A0, 0);                   // commit step s0+2
        __syncthreads();
    }
    COMPUTE(0, BA0, BA1);                // step 124

    // epilogue: + node@b, relu, store fp32
    #pragma unroll
    for (int rf = 0; rf < 5; ++rf) {
        #pragma unroll
        for (int cf = 0; cf < 2; ++cf) {
            int fl = w * 32 + cf * 16 + (lane & 15);
            #pragma unroll
            for (int r = 0; r < 4; ++r) {
                int nl = rf * 16 + (lane >> 4) * 4 + r;
                float bias = 0.f;
                #pragma unroll 8
                for (int k = 0; k < 32; ++k) bias += nlds[nl * 32 + k] * blds[k * 256 + fl];
                float v = acc[rf][cf][r] + bias;
                out[(size_t)(m0 + nl) * 256 + fl] = v > 0.f ? v : 0.f;
            }
        }
    }
#undef LOADA
#undef WRITEA
#undef LOADB
#undef COMPUTE
}

extern "C" void kernel_launch(void* const* d_in, const int* in_sizes, int n_in,
                              void* d_out, int out_size, void* d_ws, size_t ws_size,
                              hipStream_t stream) {
    const float* h   = (const float*)d_in[0];
    const float* adj = (const float*)d_in[1];
    const float* W1  = (const float*)d_in[2];
    const float* W2  = (const float*)d_in[3];
    const float* b   = (const float*)d_in[4];
    float* out = (float*)d_out;

    char* ws = (char*)d_ws;
    float* node   = (float*)ws;                               // 2,560,000 B
    short* P      = (short*)(ws + 2560000);                   // 4,194,304 B
    short* xpre_t = (short*)(ws + 2560000 + 4194304);         // 10,240,000 B

    k_node  <<<2500, 256, 0, stream>>>(h, W1, node);
    k_packW2<<<1024, 256, 0, stream>>>(W2, P);
    k_xpre  <<<313,  256, 0, stream>>>(h, node, P, xpre_t);
    k_aggr  <<<250,  512, 0, stream>>>(adj, xpre_t, node, b, out);
}

// Round 3
// 868.316 us; speedup vs baseline: 1.3748x; 1.0096x over previous
//
#include <hip/hip_runtime.h>
#include <hip/hip_bf16.h>

#define Nn 20000
#define Dd 256
#define Ff 256
#define Kc 32

typedef __attribute__((ext_vector_type(8))) short short8;
typedef __attribute__((ext_vector_type(4))) short short4_t;
typedef __attribute__((ext_vector_type(4))) float float4_t;

static __device__ __forceinline__ short f2bf(float x) {
    union { float f; unsigned u; } v; v.f = x;
    unsigned r = v.u + 0x7FFFu + ((v.u >> 16) & 1u);   // round-to-nearest-even
    return (short)(r >> 16);
}
static __device__ __forceinline__ short4_t cvt4(float4_t v) {
    short4_t r; r[0] = f2bf(v[0]); r[1] = f2bf(v[1]); r[2] = f2bf(v[2]); r[3] = f2bf(v[3]);
    return r;
}

// ---------------- K1: node = h @ W1  [N,32] fp32 ----------------
__global__ __launch_bounds__(256) void k_node(const float* __restrict__ h,
                                              const float* __restrict__ W1,
                                              float* __restrict__ node) {
    int t = blockIdx.x * 256 + threadIdx.x;     // N*32 threads
    int n = t >> 5, k = t & 31;
    if (n >= Nn) return;
    const float4_t* hr = (const float4_t*)(h + (size_t)n * Dd);
    float s = 0.f;
    #pragma unroll 8
    for (int d4 = 0; d4 < 64; ++d4) {
        float4_t hv = hr[d4];
        #pragma unroll
        for (int j = 0; j < 4; ++j) s += hv[j] * W1[(d4 * 4 + j) * Kc + k];
    }
    node[n * Kc + k] = s;
}

// ------- K2: pack W2 (fp32 [32][256][256]) -> bf16 B-fragment order -------
__global__ __launch_bounds__(256) void k_packW2(const float* __restrict__ W2,
                                                short* __restrict__ P) {
    int t = blockIdx.x * 256 + threadIdx.x;     // 262144 threads
    int lane = t & 63;
    int cf = (t >> 6) & 15;
    int dc = (t >> 10) & 7;
    int kk = t >> 13;
    int col = cf * 16 + (lane & 15);
    int d0  = dc * 32 + (lane >> 4) * 8;
    const float* src = W2 + ((size_t)(kk * Dd + d0)) * Ff + col;
    short8 v;
    #pragma unroll
    for (int j = 0; j < 8; ++j) v[j] = f2bf(src[(size_t)j * Ff]);
    *(short8*)(P + (size_t)t * 8) = v;
}

// ---------------- K3: x_pre, stored transposed bf16 [256][20000] ----------------
__global__ __launch_bounds__(256, 2) void k_xpre(const float* __restrict__ h,
                                                 const float* __restrict__ node,
                                                 const short* __restrict__ P,
                                                 short* __restrict__ xpre_t) {
    __shared__ short hlds[64 * 264];        // bf16 h tile, padded stride 264
    __shared__ float ntl[32 * 64];          // node transposed [kk][n_local]
    int t = threadIdx.x;
    int n0 = blockIdx.x * 64;

    #pragma unroll
    for (int i = 0; i < 16; ++i) {
        int c = t + i * 256;                // 4096 float4 chunks
        int row = c >> 6, cc = c & 63;
        int n = n0 + row; if (n > Nn - 1) n = Nn - 1;
        float4_t v = *(const float4_t*)(h + (size_t)n * Dd + cc * 4);
        *(short4_t*)&hlds[row * 264 + cc * 4] = cvt4(v);
    }
    #pragma unroll
    for (int i = 0; i < 8; ++i) {
        int idx = t + i * 256;              // 2048
        int nl = idx >> 5, k = idx & 31;
        int n = n0 + nl; if (n > Nn - 1) n = Nn - 1;
        ntl[k * 64 + nl] = node[(size_t)n * Kc + k];
    }
    __syncthreads();

    int lane = t & 63, w = t >> 6;
    int arow = lane & 15;
    int asel = (lane >> 4) * 8;
    float4_t acc[4][4];
    #pragma unroll
    for (int a = 0; a < 4; ++a)
        #pragma unroll
        for (int b2 = 0; b2 < 4; ++b2) acc[a][b2] = (float4_t){0.f, 0.f, 0.f, 0.f};

    for (int kk = 0; kk < 32; ++kk) {
        float4_t T[4][4];
        #pragma unroll
        for (int a = 0; a < 4; ++a)
            #pragma unroll
            for (int b2 = 0; b2 < 4; ++b2) T[a][b2] = (float4_t){0.f, 0.f, 0.f, 0.f};
        #pragma unroll
        for (int dc = 0; dc < 8; ++dc) {
            short8 af[4], bfr[4];
            #pragma unroll
            for (int rf = 0; rf < 4; ++rf)
                af[rf] = *(const short8*)&hlds[(rf * 16 + arow) * 264 + dc * 32 + asel];
            #pragma unroll
            for (int cf = 0; cf < 4; ++cf)
                bfr[cf] = *(const short8*)(P + ((size_t)(((kk * 8 + dc) * 16 + w * 4 + cf) * 64 + lane)) * 8);
            #pragma unroll
            for (int rf = 0; rf < 4; ++rf)
                #pragma unroll
                for (int cf = 0; cf < 4; ++cf)
                    T[rf][cf] = __builtin_amdgcn_mfma_f32_16x16x32_bf16(af[rf], bfr[cf], T[rf][cf], 0, 0, 0);
        }
        #pragma unroll
        for (int rf = 0; rf < 4; ++rf) {
            float4_t sc = *(const float4_t*)&ntl[kk * 64 + rf * 16 + (lane >> 4) * 4];
            #pragma unroll
            for (int cf = 0; cf < 4; ++cf)
                #pragma unroll
                for (int r = 0; r < 4; ++r)
                    acc[rf][cf][r] += sc[r] * T[rf][cf][r];
        }
    }

    #pragma unroll
    for (int rf = 0; rf < 4; ++rf) {
        int nl = rf * 16 + (lane >> 4) * 4;
        #pragma unroll
        for (int cf = 0; cf < 4; ++cf) {
            int f = w * 64 + cf * 16 + (lane & 15);
            #pragma unroll
            for (int r = 0; r < 4; ++r) {
                int n = n0 + nl + r;
                if (n < Nn) xpre_t[(size_t)f * Nn + n] = f2bf(acc[rf][cf][r]);
            }
        }
    }
}

// ---------------- K4: out = relu(adj @ x_pre + node @ b) ----------------
// BM=80 (250 blocks), BN=256, BK=160 (125 steps), 512 threads (8 waves)
// Raw s_barrier (lgkmcnt-only) so the 2-step adj / 1-step B register
// pipelines stay in flight across steps (T3/T4). 1 barrier per step.
#define BM 80
#define BK 160
#define ASTR 168            // alds row stride in shorts (336B = 21*16, b128-aligned)
#define NSTEP 125

__global__ __launch_bounds__(512, 2) void k_aggr(const float* __restrict__ adj,
                                                 const short* __restrict__ xpre_t,
                                                 const float* __restrict__ node,
                                                 const float* __restrict__ bb,
                                                 float* __restrict__ out) {
    __shared__ short alds[2][BM * ASTR];    // 2 x 26.9 KB
    __shared__ float nlds[BM * 32];         // 10.24 KB
    __shared__ float blds[32 * 256];        // 32.77 KB

    const int t = threadIdx.x;
    const int m0 = blockIdx.x * BM;
    const int lane = t & 63, w = t >> 6;
    const int kb = (lane >> 4) * 8;

    // stage node tile + b for the epilogue (visibility via loop barriers)
    #pragma unroll
    for (int i = 0; i < 5; ++i) { int idx = t + i * 512; nlds[idx] = node[(size_t)m0 * 32 + idx]; }
    #pragma unroll
    for (int i = 0; i < 4; ++i) { int idx = t + i * 512; *(float4_t*)&blds[idx * 4] = *(const float4_t*)(bb + (size_t)idx * 4); }

    // adj staging geometry: 80*160 floats = 3200 float4 chunks/step; 6-7 per thread
    const bool val7 = (t < 128);
    long gbase[7]; int loff[7];
    #pragma unroll
    for (int i = 0; i < 7; ++i) {
        int c = t + i * 512; if (c >= 3200) c = 0;
        int row = c / 40, col = c % 40;     // 40 float4 per row
        gbase[i] = (long)(m0 + row) * Nn + col * 4;
        loff[i]  = row * ASTR + col * 4;
    }
    // xpre B-frag bases (this wave's two 16-col fragments)
    const long xb0 = (long)(w * 32 + (lane & 15)) * Nn + kb;
    const long xb1 = xb0 + 16L * Nn;

#define LOADA(dst, s_) do { _Pragma("unroll") for (int i = 0; i < 7; ++i) \
        if (i < 6 || val7) dst[i] = *(const float4_t*)(adj + gbase[i] + (long)(s_) * BK); } while (0)

#define WRITEA(src, buf_) do { _Pragma("unroll") for (int i = 0; i < 7; ++i) \
        if (i < 6 || val7) *(short4_t*)&alds[buf_][loff[i]] = cvt4(src[i]); } while (0)

#define LOADB(d0_, d1_, s_) do { _Pragma("unroll") for (int dc = 0; dc < 5; ++dc) { \
        d0_[dc] = *(const short8*)(xpre_t + xb0 + (long)(s_) * BK + dc * 32); \
        d1_[dc] = *(const short8*)(xpre_t + xb1 + (long)(s_) * BK + dc * 32); } } while (0)

#define COMPUTE(buf_, B0_, B1_) do { _Pragma("unroll") for (int dc = 0; dc < 5; ++dc) { \
        _Pragma("unroll") for (int rf = 0; rf < 5; ++rf) { \
            short8 afr = *(const short8*)&alds[buf_][(rf * 16 + (lane & 15)) * ASTR + dc * 32 + kb]; \
            acc[rf][0] = __builtin_amdgcn_mfma_f32_16x16x32_bf16(afr, B0_[dc], acc[rf][0], 0, 0, 0); \
            acc[rf][1] = __builtin_amdgcn_mfma_f32_16x16x32_bf16(afr, B1_[dc], acc[rf][1], 0, 0, 0); } } } while (0)

// Raw barrier: LDS visibility only; global prefetches stay in flight (T3/T4).
#define SYNC() do { asm volatile("s_waitcnt lgkmcnt(0)" ::: "memory"); \
                    __builtin_amdgcn_s_barrier(); } while (0)

    float4_t acc[5][2];
    #pragma unroll
    for (int rf = 0; rf < 5; ++rf)
        #pragma unroll
        for (int cf = 0; cf < 2; ++cf) acc[rf][cf] = (float4_t){0.f, 0.f, 0.f, 0.f};

    float4_t A0[7], A1[7];
    short8 BA0[5], BA1[5], BB0[5], BB1[5];

    // prologue: adj 2-deep, B 2-deep; commit step 0 to LDS
    LOADA(A0, 0);
    LOADA(A1, 1);
    LOADB(BA0, BA1, 0);
    LOADB(BB0, BB1, 1);
    WRITEA(A0, 0);                       // counted vmcnt on A0's loads only
    SYNC();

    #pragma unroll 1
    for (int p = 0; p < 62; ++p) {
        const int s0 = 2 * p;
        // even step s0: compute buf0 with BA; refill A(s0+2), BA<-B(s0+2)
        LOADA(A0, s0 + 2);
        COMPUTE(0, BA0, BA1);
        LOADB(BA0, BA1, s0 + 2);
        WRITEA(A1, 1);                   // commit step s0+1
        SYNC();
        // odd step s0+1: compute buf1 with BB; refill A(s0+3), BB<-B(s0+3)
        if (s0 + 3 < NSTEP) LOADA(A1, s0 + 3);
        COMPUTE(1, BB0, BB1);
        if (s0 + 3 < NSTEP) LOADB(BB0, BB1, s0 + 3);
        WRITEA(A0, 0);                   // commit step s0+2
        SYNC();
    }
    COMPUTE(0, BA0, BA1);                // step 124

    // epilogue: + node@b, relu, store fp32
    #pragma unroll
    for (int rf = 0; rf < 5; ++rf) {
        #pragma unroll
        for (int cf = 0; cf < 2; ++cf) {
            int fl = w * 32 + cf * 16 + (lane & 15);
            #pragma unroll
            for (int r = 0; r < 4; ++r) {
                int nl = rf * 16 + (lane >> 4) * 4 + r;
                float bias = 0.f;
                #pragma unroll 8
                for (int k = 0; k < 32; ++k) bias += nlds[nl * 32 + k] * blds[k * 256 + fl];
                float v = acc[rf][cf][r] + bias;
                out[(size_t)(m0 + nl) * 256 + fl] = v > 0.f ? v : 0.f;
            }
        }
    }
#undef LOADA
#undef WRITEA
#undef LOADB
#undef COMPUTE
#undef SYNC
}

extern "C" void kernel_launch(void* const* d_in, const int* in_sizes, int n_in,
                              void* d_out, int out_size, void* d_ws, size_t ws_size,
                              hipStream_t stream) {
    const float* h   = (const float*)d_in[0];
    const float* adj = (const float*)d_in[1];
    const float* W1  = (const float*)d_in[2];
    const float* W2  = (const float*)d_in[3];
    const float* b   = (const float*)d_in[4];
    float* out = (float*)d_out;

    char* ws = (char*)d_ws;
    float* node   = (float*)ws;                               // 2,560,000 B
    short* P      = (short*)(ws + 2560000);                   // 4,194,304 B
    short* xpre_t = (short*)(ws + 2560000 + 4194304);         // 10,240,000 B

    k_node  <<<2500, 256, 0, stream>>>(h, W1, node);
    k_packW2<<<1024, 256, 0, stream>>>(W2, P);
    k_xpre  <<<313,  256, 0, stream>>>(h, node, P, xpre_t);
    k_aggr  <<<250,  512, 0, stream>>>(adj, xpre_t, node, b, out);
}